// Round 1
// baseline (383.052 us; speedup 1.0000x reference)
//
#include <hip/hip_runtime.h>

#define NN 24576
#define DD 32
#define KK 17
#define PP 20

// Bernstein basis of order 16: b[k] = C(16,k) * x^k * (1-x)^(16-k)
__device__ __forceinline__ void bern17(float x, float* b) {
    const float binom[KK] = {1.f, 16.f, 120.f, 560.f, 1820.f, 4368.f, 8008.f, 11440.f,
                             12870.f, 11440.f, 8008.f, 4368.f, 1820.f, 560.f, 120.f, 16.f, 1.f};
    const float y = 1.0f - x;
    b[0] = 1.0f;
#pragma unroll
    for (int k = 1; k < KK; ++k) b[k] = b[k - 1] * x;   // b[k] = x^k
    float yp = 1.0f;
#pragma unroll
    for (int k = KK - 1; k >= 0; --k) {                  // multiply (1-x)^(16-k) * binom
        b[k] = b[k] * yp * binom[k];
        yp *= y;
    }
}

// Precompute var-chain weights: wv[d,p,k,j] = exp(varw[d,p,k,j]) * sc2[j]
//                               wv0[p,k]    = exp(varw0[p,0,k]) * sc2[k]
__global__ void prep_var(const float* __restrict__ varw, const float* __restrict__ varw0,
                         const float* __restrict__ prior_sc,
                         float* __restrict__ wv, float* __restrict__ wv0) {
    const int E1 = (DD - 1) * PP * KK * KK;
    int idx = blockIdx.x * blockDim.x + threadIdx.x;
    if (idx < E1) {
        int j = idx % KK;
        float s = prior_sc[j];
        wv[idx] = expf(varw[idx]) * s * s;
    } else if (idx < E1 + PP * KK) {
        int i = idx - E1;
        int k = i % KK;
        float s = prior_sc[k];
        wv0[i] = expf(varw0[i]) * s * s;
    }
}

// Transpose X [N,D] -> XT [D,N] so chain-kernel loads are lane-coalesced.
__global__ void transpose_x(const float* __restrict__ X, float* __restrict__ XT) {
    __shared__ float t[32][33];
    const int n0 = blockIdx.x * 32;
    for (int r = threadIdx.y; r < 32; r += 8)
        t[r][threadIdx.x] = X[(n0 + r) * DD + threadIdx.x];
    __syncthreads();
    for (int d = threadIdx.y; d < 32; d += 8)
        XT[d * NN + n0 + threadIdx.x] = t[threadIdx.x][d];
}

// Fused mean+var chain: one thread per (p,n), both 17-wide states live in
// VGPRs. 578 FMAs/iter of independent work per wave hides the scalar-W-load
// and x-load latency that left the split kernels at 42% VALUBusy.
__global__ __launch_bounds__(256, 4) void bez_fused(
    const float* __restrict__ Xb,       // XT [DD,NN] (or X [NN,DD] fallback)
    const int sx_d, const int sx_n,     // strides: x = Xb[pd*sx_d + n*sx_n]
    const float* __restrict__ mw0,      // [PP,KK] meanw0
    const float* __restrict__ mW,       // [DD-1,PP,KK,KK] meanw
    const float* __restrict__ vw0,      // [PP,KK] pre-scaled var w0
    const float* __restrict__ vW,       // [DD-1,PP,KK,KK] pre-scaled var W
    const float* __restrict__ post_prec,// [PP]
    const int* __restrict__ perm,       // [PP,DD]
    float* __restrict__ out)            // [2*NN]
{
    const int p = blockIdx.y;
    const int n = blockIdx.x * blockDim.x + threadIdx.x;
    const int* __restrict__ pp = perm + p * DD;

    float fm[KK], fv[KK], b[KK];

    {
        const int pd = pp[0];
        const float x = Xb[pd * sx_d + n * sx_n];
        bern17(x, b);
        const float* __restrict__ m0 = mw0 + p * KK;
        const float* __restrict__ v0 = vw0 + p * KK;
#pragma unroll
        for (int k = 0; k < KK; ++k) {
            fm[k] = m0[k] * b[k];
            fv[k] = v0[k] * (b[k] * b[k]);
        }
    }

#pragma unroll 1
    for (int d = 1; d < DD; ++d) {
        const int pd = pp[d];
        // Issue x-load at iteration top; it is consumed only AFTER the FMA
        // block below (bern17 moved late) -> ~300cy L2 latency hidden.
        const float x = Xb[pd * sx_d + n * sx_n];

        const float* __restrict__ Wm = mW + ((size_t)(d - 1) * PP + p) * (KK * KK);
        const float* __restrict__ Wv = vW + ((size_t)(d - 1) * PP + p) * (KK * KK);

        float fmn[KK], fvn[KK];
#pragma unroll
        for (int j = 0; j < KK; ++j) { fmn[j] = 0.0f; fvn[j] = 0.0f; }

#pragma unroll
        for (int k = 0; k < KK; ++k) {
            const float am = fm[k];
            const float av = fv[k];
#pragma unroll
            for (int j = 0; j < KK; ++j) {
                fmn[j] = fmaf(am, Wm[k * KK + j], fmn[j]);  // uniform -> scalar loads
                fvn[j] = fmaf(av, Wv[k * KK + j], fvn[j]);
            }
        }

        bern17(x, b);
#pragma unroll
        for (int j = 0; j < KK; ++j) {
            fm[j] = fmn[j] * b[j];
            fv[j] = fvn[j] * (b[j] * b[j]);
        }
    }

    float sm = 0.0f, sv = 0.0f;
#pragma unroll
    for (int j = 0; j < KK; ++j) { sm += fm[j]; sv += fv[j]; }
    sv /= post_prec[p];

    atomicAdd(&out[n], sm);
    atomicAdd(&out[NN + n], sv);
}

extern "C" void kernel_launch(void* const* d_in, const int* in_sizes, int n_in,
                              void* d_out, int out_size, void* d_ws, size_t ws_size,
                              hipStream_t stream) {
    const float* X    = (const float*)d_in[0];  // Xnew [N, D]
    const float* mw0  = (const float*)d_in[1];  // meanw0 [P,1,K]
    const float* mw   = (const float*)d_in[2];  // meanw [D-1,P,K,K]
    const float* vw0  = (const float*)d_in[3];  // varw0 [P,1,K]
    const float* vw   = (const float*)d_in[4];  // varw [D-1,P,K,K]
    const float* psc  = (const float*)d_in[5];  // prior_sc [K,1]
    const float* ppr  = (const float*)d_in[6];  // post_prec [P]
    const int*   perm = (const int*)d_in[7];    // perm [P,D]
    float* out = (float*)d_out;

    const size_t wv_elems  = (size_t)(DD - 1) * PP * KK * KK;
    const size_t wv0_elems = (size_t)PP * KK;
    const size_t xt_elems  = (size_t)DD * NN;

    float* wv  = (float*)d_ws;                 // [D-1,P,K,K]
    float* wv0 = wv + wv_elems;                // [P,K]
    float* XT  = wv0 + wv0_elems;              // [D,N] (if it fits)

    const size_t need = (wv_elems + wv0_elems + xt_elems) * sizeof(float);
    const bool use_xt = (ws_size >= need);

    hipMemsetAsync(d_out, 0, (size_t)out_size * sizeof(float), stream);

    const int E = (DD - 1) * PP * KK * KK + PP * KK;
    prep_var<<<dim3((E + 255) / 256), dim3(256), 0, stream>>>(vw, vw0, psc, wv, wv0);

    const float* Xb = X;
    int sx_d = 1, sx_n = DD;
    if (use_xt) {
        transpose_x<<<dim3(NN / 32), dim3(32, 8), 0, stream>>>(X, XT);
        Xb = XT; sx_d = NN; sx_n = 1;
    }

    dim3 grid(NN / 256, PP), blk(256);
    bez_fused<<<grid, blk, 0, stream>>>(Xb, sx_d, sx_n, mw0, mw, wv0, wv, ppr, perm, out);
}

// Round 2
// 301.125 us; speedup vs baseline: 1.2721x; 1.2721x over previous
//
#include <hip/hip_runtime.h>

#define NN 24576
#define DD 32
#define KK 17
#define PP 20

// Bernstein basis of order 16: b[k] = C(16,k) * x^k * (1-x)^(16-k)
__device__ __forceinline__ void bern17(float x, float* b) {
    const float binom[KK] = {1.f, 16.f, 120.f, 560.f, 1820.f, 4368.f, 8008.f, 11440.f,
                             12870.f, 11440.f, 8008.f, 4368.f, 1820.f, 560.f, 120.f, 16.f, 1.f};
    const float y = 1.0f - x;
    b[0] = 1.0f;
#pragma unroll
    for (int k = 1; k < KK; ++k) b[k] = b[k - 1] * x;   // b[k] = x^k
    float yp = 1.0f;
#pragma unroll
    for (int k = KK - 1; k >= 0; --k) {                  // multiply (1-x)^(16-k) * binom
        b[k] = b[k] * yp * binom[k];
        yp *= y;
    }
}

// Precompute var-chain weights: wv[d,p,k,j] = exp(varw[d,p,k,j]) * sc2[j]
//                               wv0[p,k]    = exp(varw0[p,0,k]) * sc2[k]
__global__ void prep_var(const float* __restrict__ varw, const float* __restrict__ varw0,
                         const float* __restrict__ prior_sc,
                         float* __restrict__ wv, float* __restrict__ wv0) {
    const int E1 = (DD - 1) * PP * KK * KK;
    int idx = blockIdx.x * blockDim.x + threadIdx.x;
    if (idx < E1) {
        int j = idx % KK;
        float s = prior_sc[j];
        wv[idx] = expf(varw[idx]) * s * s;
    } else if (idx < E1 + PP * KK) {
        int i = idx - E1;
        int k = i % KK;
        float s = prior_sc[k];
        wv0[i] = expf(varw0[i]) * s * s;
    }
}

// Transpose X [N,D] -> XT [D,N] so chain-kernel loads are lane-coalesced.
__global__ void transpose_x(const float* __restrict__ X, float* __restrict__ XT) {
    __shared__ float t[32][33];
    const int n0 = blockIdx.x * 32;
    for (int r = threadIdx.y; r < 32; r += 8)
        t[r][threadIdx.x] = X[(n0 + r) * DD + threadIdx.x];
    __syncthreads();
    for (int d = threadIdx.y; d < 32; d += 8)
        XT[d * NN + n0 + threadIdx.x] = t[threadIdx.x][d];
}

// One thread per (p, n); ONE chain (mean or var) per thread -> ~24 VGPRs,
// no spill. Both chain types dispatched in one grid (blockIdx.z selects),
// so mean-blocks and var-blocks are co-resident per CU: one chain's FMAs
// fill the other's s_load/dep-chain stall slots.
__global__ __launch_bounds__(256, 4) void bez_chain2(
    const float* __restrict__ Xb,       // XT [DD,NN] (or X [NN,DD] fallback)
    const int sx_d, const int sx_n,     // strides: x = Xb[pd*sx_d + n*sx_n]
    const float* __restrict__ mw0,      // [PP,KK] meanw0
    const float* __restrict__ mW,       // [DD-1,PP,KK,KK] meanw
    const float* __restrict__ vw0,      // [PP,KK] pre-scaled var w0
    const float* __restrict__ vW,       // [DD-1,PP,KK,KK] pre-scaled var W
    const float* __restrict__ post_prec,// [PP]
    const int* __restrict__ perm,       // [PP,DD]
    float* __restrict__ out)            // [2*NN]
{
    const bool VAR = (blockIdx.z != 0);          // block-uniform branch
    const int p = blockIdx.y;
    const int n = blockIdx.x * blockDim.x + threadIdx.x;
    const int* __restrict__ pp = perm + p * DD;

    const float* __restrict__ w0 = (VAR ? vw0 : mw0);
    const float* __restrict__ W  = (VAR ? vW  : mW);

    float f[KK], b[KK];

    {
        const int pd = pp[0];
        const float x = Xb[pd * sx_d + n * sx_n];
        bern17(x, b);
        if (VAR) {
#pragma unroll
            for (int k = 0; k < KK; ++k) b[k] *= b[k];
        }
        const float* __restrict__ w0p = w0 + p * KK;
#pragma unroll
        for (int k = 0; k < KK; ++k) f[k] = w0p[k] * b[k];
    }

    for (int d = 1; d < DD; ++d) {
        const int pd = pp[d];
        const float x = Xb[pd * sx_d + n * sx_n];
        bern17(x, b);
        if (VAR) {
#pragma unroll
            for (int k = 0; k < KK; ++k) b[k] *= b[k];
        }

        const float* __restrict__ Wd = W + ((size_t)(d - 1) * PP + p) * (KK * KK);

        float fn[KK];
#pragma unroll
        for (int j = 0; j < KK; ++j) fn[j] = 0.0f;

#pragma unroll
        for (int k = 0; k < KK; ++k) {
            const float fk = f[k];
#pragma unroll
            for (int j = 0; j < KK; ++j)
                fn[j] = fmaf(fk, Wd[k * KK + j], fn[j]);   // uniform row -> scalar loads
        }
#pragma unroll
        for (int j = 0; j < KK; ++j) f[j] = fn[j] * b[j];
    }

    float s = 0.0f;
#pragma unroll
    for (int j = 0; j < KK; ++j) s += f[j];
    if (VAR) s /= post_prec[p];

    atomicAdd(&out[(VAR ? NN : 0) + n], s);
}

extern "C" void kernel_launch(void* const* d_in, const int* in_sizes, int n_in,
                              void* d_out, int out_size, void* d_ws, size_t ws_size,
                              hipStream_t stream) {
    const float* X    = (const float*)d_in[0];  // Xnew [N, D]
    const float* mw0  = (const float*)d_in[1];  // meanw0 [P,1,K]
    const float* mw   = (const float*)d_in[2];  // meanw [D-1,P,K,K]
    const float* vw0  = (const float*)d_in[3];  // varw0 [P,1,K]
    const float* vw   = (const float*)d_in[4];  // varw [D-1,P,K,K]
    const float* psc  = (const float*)d_in[5];  // prior_sc [K,1]
    const float* ppr  = (const float*)d_in[6];  // post_prec [P]
    const int*   perm = (const int*)d_in[7];    // perm [P,D]
    float* out = (float*)d_out;

    const size_t wv_elems  = (size_t)(DD - 1) * PP * KK * KK;
    const size_t wv0_elems = (size_t)PP * KK;
    const size_t xt_elems  = (size_t)DD * NN;

    float* wv  = (float*)d_ws;                 // [D-1,P,K,K]
    float* wv0 = wv + wv_elems;                // [P,K]
    float* XT  = wv0 + wv0_elems;              // [D,N] (if it fits)

    const size_t need = (wv_elems + wv0_elems + xt_elems) * sizeof(float);
    const bool use_xt = (ws_size >= need);

    hipMemsetAsync(d_out, 0, (size_t)out_size * sizeof(float), stream);

    const int E = (DD - 1) * PP * KK * KK + PP * KK;
    prep_var<<<dim3((E + 255) / 256), dim3(256), 0, stream>>>(vw, vw0, psc, wv, wv0);

    const float* Xb = X;
    int sx_d = 1, sx_n = DD;
    if (use_xt) {
        transpose_x<<<dim3(NN / 32), dim3(32, 8), 0, stream>>>(X, XT);
        Xb = XT; sx_d = NN; sx_n = 1;
    }

    dim3 grid(NN / 256, PP, 2), blk(256);
    bez_chain2<<<grid, blk, 0, stream>>>(Xb, sx_d, sx_n, mw0, mw, wv0, wv, ppr, perm, out);
}